// Round 1
// baseline (308.096 us; speedup 1.0000x reference)
//
#include <hip/hip_runtime.h>
#include <math.h>

// Problem constants (match setup_inputs)
constexpr int N_NODES = 7650;
constexpr int F_FEAT  = 745;
constexpr int E_EDGES = 238162;

// Workspace layout (float offsets, 256B-aligned blocks)
constexpr size_t OFF_CF  = 0;       // 16  jacobi coefficients
constexpr size_t OFF_BU  = 64;      // 9   b_j^T U1
constexpr size_t OFF_R   = 128;     // 32  U0^T [P | s]  (8 x 4)
constexpr size_t OFF_C1  = 192;     // 2235 = F*3  (W1 @ U1)
constexpr size_t OFF_DIS = 2432;    // 7650 deg -> dis (in place)
constexpr size_t OFF_W   = 10112;   // 238162 edge weights
constexpr size_t OFF_B0  = 248320;  // N*4 poly state x0 (3 cols + ones col)
constexpr size_t OFF_B1  = 279040;  // x1
constexpr size_t OFF_B2  = 309760;  // x2
constexpr size_t OFF_B3  = 340480;  // x3
constexpr size_t OFF_AX  = 371200;  // spmm scratch

// ---------------- degree / weights ----------------
__global__ void deg_kernel(const int* __restrict__ row, const float* __restrict__ attr,
                           float* __restrict__ deg) {
    int e = blockIdx.x * blockDim.x + threadIdx.x;
    if (e < E_EDGES) atomicAdd(&deg[row[e]], attr[e]);
}

__global__ void dis_kernel(float* __restrict__ deg_dis) {
    int i = blockIdx.x * blockDim.x + threadIdx.x;
    if (i < N_NODES) {
        float d = deg_dis[i];
        deg_dis[i] = (d > 0.0f) ? 1.0f / sqrtf(fmaxf(d, 1e-12f)) : 0.0f;
    }
}

__global__ void w_kernel(const int* __restrict__ row, const int* __restrict__ col,
                         const float* __restrict__ attr, const float* __restrict__ dis,
                         float* __restrict__ w) {
    int e = blockIdx.x * blockDim.x + threadIdx.x;
    if (e < E_EDGES) w[e] = dis[row[e]] * attr[e] * dis[col[e]];
}

// ---------------- jacobi scalar coefficients ----------------
__global__ void coef_kernel(const float* __restrict__ alphas_raw, float* __restrict__ cf) {
    if (threadIdx.x == 0 && blockIdx.x == 0) {
        float al[4];
        #pragma unroll
        for (int i = 0; i < 4; ++i) al[i] = tanhf(alphas_raw[i]);
        const float a = 1.f, b = 1.f, l = -1.f, r = 1.f;
        // L = 1
        float coef1 = (a - b) * 0.5f - (a + b + 2.f) * 0.5f * (l + r) / (r - l);
        float coef2 = (a + b + 2.f) / (r - l);
        cf[0] = al[0] * coef1;
        cf[1] = al[0] * coef2;
        // L = 2, 3
        for (int L = 2; L <= 3; ++L) {
            float Lf = (float)L;
            float coef_l     = 2.f * Lf * (Lf + a + b) * (2.f * Lf - 2.f + a + b);
            float coef_lm1_1 = (2.f * Lf + a + b - 1.f) * (2.f * Lf + a + b) * (2.f * Lf + a + b - 2.f);
            float coef_lm1_2 = (2.f * Lf + a + b - 1.f) * (a * a - b * b);
            float coef_lm2   = 2.f * (Lf - 1.f + a) * (Lf - 1.f + b) * (2.f * Lf + a + b);
            float tmp1   = al[L - 1] * (coef_lm1_1 / coef_l);
            float tmp2   = al[L - 1] * (coef_lm1_2 / coef_l);
            float tmp3   = al[L - 1] * al[L - 2] * (coef_lm2 / coef_l);
            float tmp1_2 = tmp1 * (2.f / (r - l));
            float tmp2_2 = tmp1 * ((r + l) / (r - l)) + tmp2;
            int o = 2 + (L - 2) * 3;
            cf[o + 0] = tmp1_2;
            cf[o + 1] = tmp2_2;
            cf[o + 2] = tmp3;
        }
    }
}

// ---------------- C1 = W1 @ U1  (F x 3) ----------------
__global__ void c1_kernel(const float* __restrict__ W1, const float* __restrict__ U1,
                          float* __restrict__ C1) {
    int wid  = (blockIdx.x * blockDim.x + threadIdx.x) >> 6;
    int lane = threadIdx.x & 63;
    if (wid >= F_FEAT * 3) return;
    int f = wid / 3, s = wid - f * 3;
    const float* wr = W1 + (size_t)f * F_FEAT;
    float acc = 0.f;
    for (int k = lane; k < F_FEAT; k += 64) acc += wr[k] * U1[k * 3 + s];
    #pragma unroll
    for (int off = 32; off; off >>= 1) acc += __shfl_down(acc, off);
    if (lane == 0) C1[wid] = acc;
}

// ---------------- bu[j][s] = b_j^T U1 ----------------
__global__ void bu_kernel(const float* __restrict__ b1, const float* __restrict__ b2,
                          const float* __restrict__ b3, const float* __restrict__ U1,
                          float* __restrict__ bu) {
    int o = blockIdx.x;            // 0..8
    int j = o / 3, s = o - j * 3;
    const float* bb = (j == 0) ? b1 : ((j == 1) ? b2 : b3);
    int lane = threadIdx.x;
    float acc = 0.f;
    for (int k = lane; k < F_FEAT; k += 64) acc += bb[k] * U1[k * 3 + s];
    #pragma unroll
    for (int off = 32; off; off >>= 1) acc += __shfl_down(acc, off);
    if (lane == 0) bu[o] = acc;
}

// ---------------- Z = [X @ C1 | 1]  (N x 4) ----------------
__global__ void xz_kernel(const float* __restrict__ X, const float* __restrict__ C1,
                          float4* __restrict__ Z) {
    __shared__ float sC[F_FEAT * 3];
    for (int i = threadIdx.x; i < F_FEAT * 3; i += blockDim.x) sC[i] = C1[i];
    __syncthreads();
    int wave = threadIdx.x >> 6;
    int lane = threadIdx.x & 63;
    int rowi = blockIdx.x * (blockDim.x >> 6) + wave;
    if (rowi >= N_NODES) return;
    const float* xr = X + (size_t)rowi * F_FEAT;
    float s0 = 0.f, s1 = 0.f, s2 = 0.f;
    for (int k = lane; k < F_FEAT; k += 64) {
        float xv = xr[k];
        s0 += xv * sC[k * 3 + 0];
        s1 += xv * sC[k * 3 + 1];
        s2 += xv * sC[k * 3 + 2];
    }
    #pragma unroll
    for (int off = 32; off; off >>= 1) {
        s0 += __shfl_down(s0, off);
        s1 += __shfl_down(s1, off);
        s2 += __shfl_down(s2, off);
    }
    if (lane == 0) Z[rowi] = make_float4(s0, s1, s2, 1.0f);
}

// ---------------- SpMM: out[row] += w * x[col]  (N x 4, atomics) ----------------
__global__ void spmm_kernel(const int* __restrict__ row, const int* __restrict__ col,
                            const float* __restrict__ w, const float4* __restrict__ x,
                            float* __restrict__ out) {
    int e = blockIdx.x * blockDim.x + threadIdx.x;
    if (e >= E_EDGES) return;
    int rr = row[e], cc = col[e];
    float we = w[e];
    float4 v = x[cc];
    atomicAdd(&out[rr * 4 + 0], we * v.x);
    atomicAdd(&out[rr * 4 + 1], we * v.y);
    atomicAdd(&out[rr * 4 + 2], we * v.z);
    atomicAdd(&out[rr * 4 + 3], we * v.w);
}

// ---------------- jacobi combines ----------------
__global__ void combine1_kernel(const float4* __restrict__ B0, const float4* __restrict__ Ax,
                                float4* __restrict__ B1, const float* __restrict__ cf) {
    int i = blockIdx.x * blockDim.x + threadIdx.x;
    if (i >= N_NODES) return;
    float c0 = cf[0], c1 = cf[1];
    float4 x0 = B0[i], ax = Ax[i];
    B1[i] = make_float4(c0 * x0.x + c1 * ax.x, c0 * x0.y + c1 * ax.y,
                        c0 * x0.z + c1 * ax.z, c0 * x0.w + c1 * ax.w);
}

__global__ void combineL_kernel(const float4* __restrict__ Ax, const float4* __restrict__ Xm1,
                                const float4* __restrict__ Xm2, float4* __restrict__ Xn,
                                const float* __restrict__ cf) {
    int i = blockIdx.x * blockDim.x + threadIdx.x;
    if (i >= N_NODES) return;
    float cA = cf[0], cB = cf[1], cC = cf[2];
    float4 ax = Ax[i], x1 = Xm1[i], x2 = Xm2[i];
    Xn[i] = make_float4(cA * ax.x - cB * x1.x - cC * x2.x,
                        cA * ax.y - cB * x1.y - cC * x2.y,
                        cA * ax.z - cB * x1.z - cC * x2.z,
                        cA * ax.w - cB * x1.w - cC * x2.w);
}

// ---------------- R[r][c] = sum_i U0[i,r] * (B0+B1+B2+B3)[i,c] ----------------
__global__ void reduce_kernel(const float* __restrict__ U0, const float4* __restrict__ B0,
                              const float4* __restrict__ B1, const float4* __restrict__ B2,
                              const float4* __restrict__ B3, float* __restrict__ R) {
    int i = blockIdx.x * blockDim.x + threadIdx.x;
    float acc[32];
    #pragma unroll
    for (int k = 0; k < 32; ++k) acc[k] = 0.f;
    if (i < N_NODES) {
        float4 s0 = B0[i], s1 = B1[i], s2 = B2[i], s3 = B3[i];
        float4 S = make_float4(s0.x + s1.x + s2.x + s3.x, s0.y + s1.y + s2.y + s3.y,
                               s0.z + s1.z + s2.z + s3.z, s0.w + s1.w + s2.w + s3.w);
        const float* u0 = U0 + (size_t)i * 8;
        #pragma unroll
        for (int rr = 0; rr < 8; ++rr) {
            float u = u0[rr];
            acc[rr * 4 + 0] += u * S.x;
            acc[rr * 4 + 1] += u * S.y;
            acc[rr * 4 + 2] += u * S.z;
            acc[rr * 4 + 3] += u * S.w;
        }
    }
    int lane = threadIdx.x & 63;
    #pragma unroll
    for (int k = 0; k < 32; ++k) {
        float v = acc[k];
        #pragma unroll
        for (int off = 32; off; off >>= 1) v += __shfl_down(v, off);
        if (lane == 0 && v != 0.f) atomicAdd(&R[k], v);
    }
}

// ---------------- final tiny TRL + log_softmax ----------------
__global__ void final_kernel(const float* __restrict__ R, const float* __restrict__ bu,
                             const float* __restrict__ U2, const float* __restrict__ core,
                             const float* __restrict__ U3, const float* __restrict__ trl_bias,
                             float* __restrict__ out) {
    if (threadIdx.x != 0 || blockIdx.x != 0) return;
    float M[3][8][3];
    for (int r = 0; r < 8; ++r) {
        float q = R[r * 4 + 3];
        for (int s = 0; s < 3; ++s) {
            M[0][r][s] = R[r * 4 + s] + q * bu[0 * 3 + s];
            M[1][r][s] = q * bu[1 * 3 + s];
            M[2][r][s] = q * bu[2 * 3 + s];
        }
    }
    float uvec[8];
    for (int u = 0; u < 8; ++u) uvec[u] = 0.f;
    for (int r = 0; r < 8; ++r)
        for (int s = 0; s < 3; ++s)
            for (int t = 0; t < 3; ++t) {
                float rst = 0.f;
                for (int c = 0; c < 3; ++c) rst += M[c][r][s] * U2[c * 3 + t];
                const float* cp = core + ((r * 3 + s) * 3 + t) * 8;
                for (int u = 0; u < 8; ++u) uvec[u] += rst * cp[u];
            }
    float o[8];
    float mx = -1e30f;
    for (int i = 0; i < 8; ++i) {
        float acc = trl_bias[0];
        for (int u = 0; u < 8; ++u) acc += uvec[u] * U3[i * 8 + u];
        o[i] = acc;
        mx = fmaxf(mx, acc);
    }
    float se = 0.f;
    for (int i = 0; i < 8; ++i) se += expf(o[i] - mx);
    float lse = mx + logf(se);
    for (int i = 0; i < 8; ++i) out[i] = o[i] - lse;
}

extern "C" void kernel_launch(void* const* d_in, const int* in_sizes, int n_in,
                              void* d_out, int out_size, void* d_ws, size_t ws_size,
                              hipStream_t stream) {
    const float* X          = (const float*)d_in[0];
    const int*   edge_index = (const int*)d_in[1];
    const float* edge_attr  = (const float*)d_in[2];
    const float* W1         = (const float*)d_in[3];
    const float* b1         = (const float*)d_in[4];
    const float* b2         = (const float*)d_in[6];
    const float* b3         = (const float*)d_in[8];
    const float* alphas_raw = (const float*)d_in[9];
    const float* core       = (const float*)d_in[10];
    const float* U0         = (const float*)d_in[11];
    const float* U1         = (const float*)d_in[12];
    const float* U2         = (const float*)d_in[13];
    const float* U3         = (const float*)d_in[14];
    const float* trl_bias   = (const float*)d_in[15];

    const int* row = edge_index;            // first E
    const int* col = edge_index + E_EDGES;  // next E

    float* ws  = (float*)d_ws;
    float* cf  = ws + OFF_CF;
    float* bu  = ws + OFF_BU;
    float* R   = ws + OFF_R;
    float* C1  = ws + OFF_C1;
    float* dis = ws + OFF_DIS;
    float* w   = ws + OFF_W;
    float* B0  = ws + OFF_B0;
    float* B1  = ws + OFF_B1;
    float* B2  = ws + OFF_B2;
    float* B3  = ws + OFF_B3;
    float* Ax  = ws + OFF_AX;

    const int TB = 256;
    const int gE = (E_EDGES + TB - 1) / TB;
    const int gN = (N_NODES + TB - 1) / TB;

    // degree -> dis -> edge weights
    hipMemsetAsync(dis, 0, N_NODES * sizeof(float), stream);
    deg_kernel<<<gE, TB, 0, stream>>>(row, edge_attr, dis);
    dis_kernel<<<gN, TB, 0, stream>>>(dis);
    w_kernel<<<gE, TB, 0, stream>>>(row, col, edge_attr, dis, w);

    // scalar coefficients + small dots
    coef_kernel<<<1, 64, 0, stream>>>(alphas_raw, cf);
    bu_kernel<<<9, 64, 0, stream>>>(b1, b2, b3, U1, bu);

    // C1 = W1@U1 ; Z = [X@C1 | 1]
    const int nw_c1 = F_FEAT * 3;                      // 2235 waves
    c1_kernel<<<(nw_c1 * 64 + TB - 1) / TB, TB, 0, stream>>>(W1, U1, C1);
    xz_kernel<<<(N_NODES + 3) / 4, TB, 0, stream>>>(X, C1, (float4*)B0);

    // poly iterations on N x 4
    hipMemsetAsync(Ax, 0, N_NODES * 4 * sizeof(float), stream);
    spmm_kernel<<<gE, TB, 0, stream>>>(row, col, w, (const float4*)B0, Ax);
    combine1_kernel<<<gN, TB, 0, stream>>>((const float4*)B0, (const float4*)Ax, (float4*)B1, cf);

    hipMemsetAsync(Ax, 0, N_NODES * 4 * sizeof(float), stream);
    spmm_kernel<<<gE, TB, 0, stream>>>(row, col, w, (const float4*)B1, Ax);
    combineL_kernel<<<gN, TB, 0, stream>>>((const float4*)Ax, (const float4*)B1,
                                           (const float4*)B0, (float4*)B2, cf + 2);

    hipMemsetAsync(Ax, 0, N_NODES * 4 * sizeof(float), stream);
    spmm_kernel<<<gE, TB, 0, stream>>>(row, col, w, (const float4*)B2, Ax);
    combineL_kernel<<<gN, TB, 0, stream>>>((const float4*)Ax, (const float4*)B2,
                                           (const float4*)B1, (float4*)B3, cf + 5);

    // R = U0^T [P | s]
    hipMemsetAsync(R, 0, 32 * sizeof(float), stream);
    reduce_kernel<<<gN, TB, 0, stream>>>(U0, (const float4*)B0, (const float4*)B1,
                                         (const float4*)B2, (const float4*)B3, R);

    // final tiny contraction + log_softmax
    final_kernel<<<1, 64, 0, stream>>>(R, bu, U2, core, U3, trl_bias, (float*)d_out);
}

// Round 2
// 158.955 us; speedup vs baseline: 1.9383x; 1.9383x over previous
//
#include <hip/hip_runtime.h>
#include <math.h>

// Problem constants (match setup_inputs)
constexpr int N_NODES = 7650;
constexpr int F_FEAT  = 745;
constexpr int E_EDGES = 238162;

// Workspace layout (float-word offsets, 128-word aligned blocks)
constexpr size_t OFF_CF   = 0;       // 16   unified jacobi triples (9 used)
constexpr size_t OFF_BU   = 16;      // 9    b_j^T U1
constexpr size_t OFF_R    = 32;      // 32   U0^T [P | s] (8 x 4)
constexpr size_t OFF_C1   = 64;      // 2235 = F*3 (W1 @ U1)           -> 2299
constexpr size_t OFF_DIS  = 2304;    // 7650 deg -> dis (in place)     -> 9954
constexpr size_t OFF_CNT  = 9984;    // 7650 int  edge counts          -> 17634
constexpr size_t OFF_RS   = 17664;   // 7651 int  rowstart             -> 25315
constexpr size_t OFF_CUR  = 25344;   // 7650 int  scatter cursors      -> 32994
constexpr size_t OFF_ECOL = 33024;   // 238162 int  CSR cols           -> 271186
constexpr size_t OFF_EW   = 271232;  // 238162 f32  CSR weights        -> 509394
constexpr size_t OFF_B0   = 509440;  // N*4 poly state x0 (3 cols + ones col)
constexpr size_t OFF_B1   = 540160;
constexpr size_t OFF_B2   = 570880;
constexpr size_t OFF_B3   = 601600;  // end 632200 words (~2.53 MB)

// ---------------- histogram: float degree + int counts ----------------
__global__ void hist_kernel(const int* __restrict__ row, const float* __restrict__ attr,
                            float* __restrict__ degf, int* __restrict__ cnt) {
    int e = blockIdx.x * blockDim.x + threadIdx.x;
    if (e < E_EDGES) {
        int r = row[e];
        atomicAdd(&degf[r], attr[e]);
        atomicAdd(&cnt[r], 1);
    }
}

// ---------------- single-block scan: rowstart/cursor + dis in place ----------------
__global__ void scan_kernel(const int* __restrict__ cnt, float* __restrict__ degdis,
                            int* __restrict__ rowstart, int* __restrict__ cursor) {
    __shared__ int part[256];
    const int NPT = 30;                       // 256*30 = 7680 >= 7650
    int t  = threadIdx.x;
    int lo = t * NPT;
    int hi = lo + NPT; if (hi > N_NODES) hi = N_NODES;
    if (lo > N_NODES) lo = N_NODES;
    int s = 0;
    for (int i = lo; i < hi; ++i) s += cnt[i];
    part[t] = s;
    __syncthreads();
    if (t == 0) {
        int run = 0;
        for (int i = 0; i < 256; ++i) { int v = part[i]; part[i] = run; run += v; }
    }
    __syncthreads();
    int run = part[t];
    for (int i = lo; i < hi; ++i) { rowstart[i] = run; cursor[i] = run; run += cnt[i]; }
    if (t == 255) rowstart[N_NODES] = run;    // == E_EDGES
    // dis in place
    for (int i = t; i < N_NODES; i += 256) {
        float d = degdis[i];
        degdis[i] = (d > 0.0f) ? 1.0f / sqrtf(fmaxf(d, 1e-12f)) : 0.0f;
    }
}

// ---------------- scatter edges into CSR (weights computed inline) ----------------
__global__ void scatter_kernel(const int* __restrict__ row, const int* __restrict__ col,
                               const float* __restrict__ attr, const float* __restrict__ dis,
                               int* __restrict__ cursor, int* __restrict__ ecol,
                               float* __restrict__ ew) {
    int e = blockIdx.x * blockDim.x + threadIdx.x;
    if (e >= E_EDGES) return;
    int r = row[e], c = col[e];
    float wv = dis[r] * attr[e] * dis[c];
    int p = atomicAdd(&cursor[r], 1);
    ecol[p] = c;
    ew[p]   = wv;
}

// ---------------- jacobi unified coefficient triples; also zero R ----------------
// out = cf[0]*Ax - cf[1]*x_{l-1} - cf[2]*x_{l-2}
__global__ void coef_kernel(const float* __restrict__ alphas_raw, float* __restrict__ cf,
                            float* __restrict__ R) {
    int t = threadIdx.x;
    if (t < 32) R[t] = 0.f;
    if (t == 0) {
        float al[4];
        #pragma unroll
        for (int i = 0; i < 4; ++i) al[i] = tanhf(alphas_raw[i]);
        const float a = 1.f, b = 1.f, l = -1.f, r = 1.f;
        // L = 1: al0*(coef1*x0 + coef2*Ax)
        float coef1 = (a - b) * 0.5f - (a + b + 2.f) * 0.5f * (l + r) / (r - l);
        float coef2 = (a + b + 2.f) / (r - l);
        cf[0] = al[0] * coef2;
        cf[1] = -al[0] * coef1;
        cf[2] = 0.f;
        for (int L = 2; L <= 3; ++L) {
            float Lf = (float)L;
            float coef_l     = 2.f * Lf * (Lf + a + b) * (2.f * Lf - 2.f + a + b);
            float coef_lm1_1 = (2.f * Lf + a + b - 1.f) * (2.f * Lf + a + b) * (2.f * Lf + a + b - 2.f);
            float coef_lm1_2 = (2.f * Lf + a + b - 1.f) * (a * a - b * b);
            float coef_lm2   = 2.f * (Lf - 1.f + a) * (Lf - 1.f + b) * (2.f * Lf + a + b);
            float tmp1   = al[L - 1] * (coef_lm1_1 / coef_l);
            float tmp2   = al[L - 1] * (coef_lm1_2 / coef_l);
            float tmp3   = al[L - 1] * al[L - 2] * (coef_lm2 / coef_l);
            float tmp1_2 = tmp1 * (2.f / (r - l));
            float tmp2_2 = tmp1 * ((r + l) / (r - l)) + tmp2;
            int o = 3 * (L - 1);
            cf[o + 0] = tmp1_2;
            cf[o + 1] = tmp2_2;
            cf[o + 2] = tmp3;
        }
    }
}

// ---------------- C1 = W1 @ U1  (F x 3) ----------------
__global__ void c1_kernel(const float* __restrict__ W1, const float* __restrict__ U1,
                          float* __restrict__ C1) {
    int wid  = (blockIdx.x * blockDim.x + threadIdx.x) >> 6;
    int lane = threadIdx.x & 63;
    if (wid >= F_FEAT * 3) return;
    int f = wid / 3, s = wid - f * 3;
    const float* wr = W1 + (size_t)f * F_FEAT;
    float acc = 0.f;
    for (int k = lane; k < F_FEAT; k += 64) acc += wr[k] * U1[k * 3 + s];
    #pragma unroll
    for (int off = 32; off; off >>= 1) acc += __shfl_down(acc, off);
    if (lane == 0) C1[wid] = acc;
}

// ---------------- bu[j][s] = b_j^T U1 ----------------
__global__ void bu_kernel(const float* __restrict__ b1, const float* __restrict__ b2,
                          const float* __restrict__ b3, const float* __restrict__ U1,
                          float* __restrict__ bu) {
    int o = blockIdx.x;            // 0..8
    int j = o / 3, s = o - j * 3;
    const float* bb = (j == 0) ? b1 : ((j == 1) ? b2 : b3);
    int lane = threadIdx.x;
    float acc = 0.f;
    for (int k = lane; k < F_FEAT; k += 64) acc += bb[k] * U1[k * 3 + s];
    #pragma unroll
    for (int off = 32; off; off >>= 1) acc += __shfl_down(acc, off);
    if (lane == 0) bu[o] = acc;
}

// ---------------- Z = [X @ C1 | 1]  (N x 4) ----------------
__global__ void xz_kernel(const float* __restrict__ X, const float* __restrict__ C1,
                          float4* __restrict__ Z) {
    __shared__ float sC[F_FEAT * 3];
    for (int i = threadIdx.x; i < F_FEAT * 3; i += blockDim.x) sC[i] = C1[i];
    __syncthreads();
    int wave = threadIdx.x >> 6;
    int lane = threadIdx.x & 63;
    int rowi = blockIdx.x * (blockDim.x >> 6) + wave;
    if (rowi >= N_NODES) return;
    const float* xr = X + (size_t)rowi * F_FEAT;
    float s0 = 0.f, s1 = 0.f, s2 = 0.f;
    for (int k = lane; k < F_FEAT; k += 64) {
        float xv = xr[k];
        s0 += xv * sC[k * 3 + 0];
        s1 += xv * sC[k * 3 + 1];
        s2 += xv * sC[k * 3 + 2];
    }
    #pragma unroll
    for (int off = 32; off; off >>= 1) {
        s0 += __shfl_down(s0, off);
        s1 += __shfl_down(s1, off);
        s2 += __shfl_down(s2, off);
    }
    if (lane == 0) Z[rowi] = make_float4(s0, s1, s2, 1.0f);
}

// ---------------- CSR SpMM + jacobi combine fused ----------------
// Xout[r] = cf[0]*(A Xin)[r] - cf[1]*Xm1[r] - cf[2]*Xm2[r]
__global__ void spmm_combine_kernel(const int* __restrict__ rowstart, const int* __restrict__ ecol,
                                    const float* __restrict__ ew, const float4* __restrict__ Xin,
                                    const float4* __restrict__ Xm1, const float4* __restrict__ Xm2,
                                    float4* __restrict__ Xout, const float* __restrict__ cf) {
    int rid = blockIdx.x * (blockDim.x >> 4) + (threadIdx.x >> 4);
    int sub = threadIdx.x & 15;
    if (rid >= N_NODES) return;
    int s    = rowstart[rid];
    int epos = rowstart[rid + 1];
    float ax = 0.f, ay = 0.f, az = 0.f, aw = 0.f;
    for (int e = s + sub; e < epos; e += 16) {
        float wv = ew[e];
        float4 v = Xin[ecol[e]];
        ax += wv * v.x; ay += wv * v.y; az += wv * v.z; aw += wv * v.w;
    }
    #pragma unroll
    for (int off = 8; off; off >>= 1) {
        ax += __shfl_xor(ax, off, 16);
        ay += __shfl_xor(ay, off, 16);
        az += __shfl_xor(az, off, 16);
        aw += __shfl_xor(aw, off, 16);
    }
    if (sub == 0) {
        float cA = cf[0], cB = cf[1], cC = cf[2];
        float4 x1 = Xm1[rid], x2 = Xm2[rid];
        Xout[rid] = make_float4(cA * ax - cB * x1.x - cC * x2.x,
                                cA * ay - cB * x1.y - cC * x2.y,
                                cA * az - cB * x1.z - cC * x2.z,
                                cA * aw - cB * x1.w - cC * x2.w);
    }
}

// ---------------- R[r][c] = sum_i U0[i,r] * (B0+B1+B2+B3)[i,c] ----------------
__global__ void reduce_kernel(const float* __restrict__ U0, const float4* __restrict__ B0,
                              const float4* __restrict__ B1, const float4* __restrict__ B2,
                              const float4* __restrict__ B3, float* __restrict__ R) {
    int i = blockIdx.x * blockDim.x + threadIdx.x;
    float acc[32];
    #pragma unroll
    for (int k = 0; k < 32; ++k) acc[k] = 0.f;
    if (i < N_NODES) {
        float4 s0 = B0[i], s1 = B1[i], s2 = B2[i], s3 = B3[i];
        float4 S = make_float4(s0.x + s1.x + s2.x + s3.x, s0.y + s1.y + s2.y + s3.y,
                               s0.z + s1.z + s2.z + s3.z, s0.w + s1.w + s2.w + s3.w);
        const float* u0 = U0 + (size_t)i * 8;
        #pragma unroll
        for (int rr = 0; rr < 8; ++rr) {
            float u = u0[rr];
            acc[rr * 4 + 0] += u * S.x;
            acc[rr * 4 + 1] += u * S.y;
            acc[rr * 4 + 2] += u * S.z;
            acc[rr * 4 + 3] += u * S.w;
        }
    }
    int lane = threadIdx.x & 63;
    #pragma unroll
    for (int k = 0; k < 32; ++k) {
        float v = acc[k];
        #pragma unroll
        for (int off = 32; off; off >>= 1) v += __shfl_down(v, off);
        if (lane == 0 && v != 0.f) atomicAdd(&R[k], v);
    }
}

// ---------------- final tiny TRL + log_softmax ----------------
__global__ void final_kernel(const float* __restrict__ R, const float* __restrict__ bu,
                             const float* __restrict__ U2, const float* __restrict__ core,
                             const float* __restrict__ U3, const float* __restrict__ trl_bias,
                             float* __restrict__ out) {
    if (threadIdx.x != 0 || blockIdx.x != 0) return;
    float M[3][8][3];
    for (int r = 0; r < 8; ++r) {
        float q = R[r * 4 + 3];
        for (int s = 0; s < 3; ++s) {
            M[0][r][s] = R[r * 4 + s] + q * bu[0 * 3 + s];
            M[1][r][s] = q * bu[1 * 3 + s];
            M[2][r][s] = q * bu[2 * 3 + s];
        }
    }
    float uvec[8];
    for (int u = 0; u < 8; ++u) uvec[u] = 0.f;
    for (int r = 0; r < 8; ++r)
        for (int s = 0; s < 3; ++s)
            for (int t = 0; t < 3; ++t) {
                float rst = 0.f;
                for (int c = 0; c < 3; ++c) rst += M[c][r][s] * U2[c * 3 + t];
                const float* cp = core + ((r * 3 + s) * 3 + t) * 8;
                for (int u = 0; u < 8; ++u) uvec[u] += rst * cp[u];
            }
    float o[8];
    float mx = -1e30f;
    for (int i = 0; i < 8; ++i) {
        float acc = trl_bias[0];
        for (int u = 0; u < 8; ++u) acc += uvec[u] * U3[i * 8 + u];
        o[i] = acc;
        mx = fmaxf(mx, acc);
    }
    float se = 0.f;
    for (int i = 0; i < 8; ++i) se += expf(o[i] - mx);
    float lse = mx + logf(se);
    for (int i = 0; i < 8; ++i) out[i] = o[i] - lse;
}

extern "C" void kernel_launch(void* const* d_in, const int* in_sizes, int n_in,
                              void* d_out, int out_size, void* d_ws, size_t ws_size,
                              hipStream_t stream) {
    const float* X          = (const float*)d_in[0];
    const int*   edge_index = (const int*)d_in[1];
    const float* edge_attr  = (const float*)d_in[2];
    const float* W1         = (const float*)d_in[3];
    const float* b1         = (const float*)d_in[4];
    const float* b2         = (const float*)d_in[6];
    const float* b3         = (const float*)d_in[8];
    const float* alphas_raw = (const float*)d_in[9];
    const float* core       = (const float*)d_in[10];
    const float* U0         = (const float*)d_in[11];
    const float* U1         = (const float*)d_in[12];
    const float* U2         = (const float*)d_in[13];
    const float* U3         = (const float*)d_in[14];
    const float* trl_bias   = (const float*)d_in[15];

    const int* row = edge_index;            // first E
    const int* col = edge_index + E_EDGES;  // next E

    float* ws   = (float*)d_ws;
    float* cf   = ws + OFF_CF;
    float* bu   = ws + OFF_BU;
    float* R    = ws + OFF_R;
    float* C1   = ws + OFF_C1;
    float* dis  = ws + OFF_DIS;   // float degree, then dis in place
    int*   cnt  = (int*)(ws + OFF_CNT);
    int*   rs   = (int*)(ws + OFF_RS);
    int*   cur  = (int*)(ws + OFF_CUR);
    int*   ecol = (int*)(ws + OFF_ECOL);
    float* ew   = ws + OFF_EW;
    float* B0   = ws + OFF_B0;
    float* B1   = ws + OFF_B1;
    float* B2   = ws + OFF_B2;
    float* B3   = ws + OFF_B3;

    const int TB = 256;
    const int gE = (E_EDGES + TB - 1) / TB;
    const int gN = (N_NODES + TB - 1) / TB;
    const int gR = (N_NODES + 15) / 16;     // rows per block = 16 (16 lanes/row)

    // zero degf + cnt in one memset (covers [OFF_DIS, OFF_RS))
    hipMemsetAsync(ws + OFF_DIS, 0, (OFF_RS - OFF_DIS) * sizeof(float), stream);

    // CSR build
    hist_kernel<<<gE, TB, 0, stream>>>(row, edge_attr, dis, cnt);
    scan_kernel<<<1, 256, 0, stream>>>(cnt, dis, rs, cur);
    scatter_kernel<<<gE, TB, 0, stream>>>(row, col, edge_attr, dis, cur, ecol, ew);

    // scalar coefficients (+ zero R) and small dots
    coef_kernel<<<1, 64, 0, stream>>>(alphas_raw, cf, R);
    bu_kernel<<<9, 64, 0, stream>>>(b1, b2, b3, U1, bu);

    // C1 = W1@U1 ; B0 = [X@C1 | 1]
    const int nw_c1 = F_FEAT * 3;
    c1_kernel<<<(nw_c1 * 64 + TB - 1) / TB, TB, 0, stream>>>(W1, U1, C1);
    xz_kernel<<<(N_NODES + 3) / 4, TB, 0, stream>>>(X, C1, (float4*)B0);

    // poly iterations: SpMM + combine fused, no atomics
    spmm_combine_kernel<<<gR, TB, 0, stream>>>(rs, ecol, ew, (const float4*)B0,
                                               (const float4*)B0, (const float4*)B0,
                                               (float4*)B1, cf + 0);
    spmm_combine_kernel<<<gR, TB, 0, stream>>>(rs, ecol, ew, (const float4*)B1,
                                               (const float4*)B1, (const float4*)B0,
                                               (float4*)B2, cf + 3);
    spmm_combine_kernel<<<gR, TB, 0, stream>>>(rs, ecol, ew, (const float4*)B2,
                                               (const float4*)B2, (const float4*)B1,
                                               (float4*)B3, cf + 6);

    // R = U0^T [P | s]
    reduce_kernel<<<gN, TB, 0, stream>>>(U0, (const float4*)B0, (const float4*)B1,
                                         (const float4*)B2, (const float4*)B3, R);

    // final tiny contraction + log_softmax
    final_kernel<<<1, 64, 0, stream>>>(R, bu, U2, core, U3, trl_bias, (float*)d_out);
}

// Round 3
// 105.490 us; speedup vs baseline: 2.9206x; 1.5068x over previous
//
#include <hip/hip_runtime.h>
#include <math.h>

// Problem constants (match setup_inputs)
constexpr int N_NODES = 7650;
constexpr int F_FEAT  = 745;
constexpr int E_EDGES = 238162;

// Workspace layout (float-word offsets)
constexpr size_t OFF_CF   = 0;       // 9    unified jacobi triples
constexpr size_t OFF_BU   = 16;      // 9    b_j^T U1
constexpr size_t OFF_R    = 32;      // 32   U0^T [P | s] (8 x 4)
constexpr size_t OFF_DONE = 64;      // 1    int ticket counter
constexpr size_t OFF_C1   = 128;     // 2235 = F*3 (W1 @ U1)
constexpr size_t OFF_DIS  = 2432;    // 7650 deg -> dis (in place)
constexpr size_t OFF_CNT  = 10112;   // 7650 int  edge counts
constexpr size_t OFF_RS   = 17792;   // 7651 int  rowstart
constexpr size_t OFF_CUR  = 25472;   // 7650 int  scatter cursors
constexpr size_t OFF_ECOL = 33152;   // 238162 int  CSR cols
constexpr size_t OFF_EW   = 271360;  // 238162 f32  CSR weights
constexpr size_t OFF_B0   = 509568;  // N*4 poly state x0 (3 cols + ones col)
constexpr size_t OFF_B1   = 540288;
constexpr size_t OFF_B2   = 571008;
constexpr size_t OFF_B3   = 601728;  // end ~632328 words (~2.53 MB)

// setup_kernel block roles
constexpr int ZB       = 15;                    // blocks 0..14: zero deg/cnt (15360 words)
constexpr int CB       = 15;                    // block 15: coef + zero R + done
constexpr int BU0      = 16;                    // blocks 16..24: bu
constexpr int C1B0     = 25;                    // blocks 25..: c1 (4 waves/block)
constexpr int NW_C1    = F_FEAT * 3;            // 2235 row-waves
constexpr int C1_BLKS  = (NW_C1 + 3) / 4;       // 559
constexpr int SETUP_BLOCKS = C1B0 + C1_BLKS;    // 584

// ---------------- fused setup: zero + jacobi coefs + bu + C1 ----------------
__global__ void setup_kernel(const float* __restrict__ alphas_raw, const float* __restrict__ b1,
                             const float* __restrict__ b2, const float* __restrict__ b3,
                             const float* __restrict__ U1, const float* __restrict__ W1,
                             float* __restrict__ ws) {
    int bid = blockIdx.x, t = threadIdx.x;

    if (bid < ZB) {
        // zero degf + cnt: 15360 words = 3840 float4
        float4* dst = (float4*)(ws + OFF_DIS);
        dst[bid * 256 + t] = make_float4(0.f, 0.f, 0.f, 0.f);
        return;
    }
    if (bid == CB) {
        float* R = ws + OFF_R;
        if (t < 32) R[t] = 0.f;
        if (t == 32) *((int*)(ws + OFF_DONE)) = 0;
        if (t == 0) {
            float* cf = ws + OFF_CF;
            float al[4];
            #pragma unroll
            for (int i = 0; i < 4; ++i) al[i] = tanhf(alphas_raw[i]);
            const float a = 1.f, b = 1.f, l = -1.f, r = 1.f;
            // L = 1: out = cf0*Ax - cf1*x0 - cf2*0
            float coef1 = (a - b) * 0.5f - (a + b + 2.f) * 0.5f * (l + r) / (r - l);
            float coef2 = (a + b + 2.f) / (r - l);
            cf[0] = al[0] * coef2;
            cf[1] = -al[0] * coef1;
            cf[2] = 0.f;
            for (int L = 2; L <= 3; ++L) {
                float Lf = (float)L;
                float coef_l     = 2.f * Lf * (Lf + a + b) * (2.f * Lf - 2.f + a + b);
                float coef_lm1_1 = (2.f * Lf + a + b - 1.f) * (2.f * Lf + a + b) * (2.f * Lf + a + b - 2.f);
                float coef_lm1_2 = (2.f * Lf + a + b - 1.f) * (a * a - b * b);
                float coef_lm2   = 2.f * (Lf - 1.f + a) * (Lf - 1.f + b) * (2.f * Lf + a + b);
                float tmp1   = al[L - 1] * (coef_lm1_1 / coef_l);
                float tmp2   = al[L - 1] * (coef_lm1_2 / coef_l);
                float tmp3   = al[L - 1] * al[L - 2] * (coef_lm2 / coef_l);
                float tmp1_2 = tmp1 * (2.f / (r - l));
                float tmp2_2 = tmp1 * ((r + l) / (r - l)) + tmp2;
                int o = 3 * (L - 1);
                cf[o + 0] = tmp1_2;
                cf[o + 1] = tmp2_2;
                cf[o + 2] = tmp3;
            }
        }
        return;
    }
    if (bid < BU0 + 9) {
        // bu[o] = b_j^T U1[:, s]
        if (t >= 64) return;
        int o = bid - BU0;
        int j = o / 3, s = o - j * 3;
        const float* bb = (j == 0) ? b1 : ((j == 1) ? b2 : b3);
        float acc = 0.f;
        for (int k = t; k < F_FEAT; k += 64) acc += bb[k] * U1[k * 3 + s];
        #pragma unroll
        for (int off = 32; off; off >>= 1) acc += __shfl_down(acc, off);
        if (t == 0) (ws + OFF_BU)[o] = acc;
        return;
    }
    // C1 = W1 @ U1  (F x 3): one 64-lane wave per output element
    int wid  = (bid - C1B0) * 4 + (t >> 6);
    int lane = t & 63;
    if (wid >= NW_C1) return;
    int f = wid / 3, s = wid - f * 3;
    const float* wr = W1 + (size_t)f * F_FEAT;
    float acc = 0.f;
    for (int k = lane; k < F_FEAT; k += 64) acc += wr[k] * U1[k * 3 + s];
    #pragma unroll
    for (int off = 32; off; off >>= 1) acc += __shfl_down(acc, off);
    if (lane == 0) (ws + OFF_C1)[wid] = acc;
}

// ---------------- histogram: float degree + int counts ----------------
__global__ void hist_kernel(const int* __restrict__ row, const float* __restrict__ attr,
                            float* __restrict__ degf, int* __restrict__ cnt) {
    int e = blockIdx.x * blockDim.x + threadIdx.x;
    if (e < E_EDGES) {
        int r = row[e];
        atomicAdd(&degf[r], attr[e]);
        atomicAdd(&cnt[r], 1);
    }
}

// ---------------- single-block scan: rowstart/cursor + dis in place ----------------
__global__ void scan_kernel(const int* __restrict__ cnt, float* __restrict__ degdis,
                            int* __restrict__ rowstart, int* __restrict__ cursor) {
    __shared__ int part[256];
    const int NPT = 30;                       // 256*30 = 7680 >= 7650
    int t  = threadIdx.x;
    int lo = t * NPT; if (lo > N_NODES) lo = N_NODES;
    int hi = lo + NPT; if (hi > N_NODES) hi = N_NODES;
    int s = 0;
    for (int i = lo; i < hi; ++i) s += cnt[i];
    part[t] = s;
    __syncthreads();
    // Hillis-Steele inclusive scan over 256 partials
    #pragma unroll
    for (int d = 1; d < 256; d <<= 1) {
        int v = (t >= d) ? part[t - d] : 0;
        __syncthreads();
        part[t] += v;
        __syncthreads();
    }
    int run = part[t] - s;                    // exclusive prefix
    for (int i = lo; i < hi; ++i) { rowstart[i] = run; cursor[i] = run; run += cnt[i]; }
    if (t == 255) rowstart[N_NODES] = run;    // == E_EDGES
    // dis in place
    for (int i = t; i < N_NODES; i += 256) {
        float d = degdis[i];
        degdis[i] = (d > 0.0f) ? 1.0f / sqrtf(fmaxf(d, 1e-12f)) : 0.0f;
    }
}

// ---------------- scatter edges into CSR (weights computed inline) ----------------
__global__ void scatter_kernel(const int* __restrict__ row, const int* __restrict__ col,
                               const float* __restrict__ attr, const float* __restrict__ dis,
                               int* __restrict__ cursor, int* __restrict__ ecol,
                               float* __restrict__ ew) {
    int e = blockIdx.x * blockDim.x + threadIdx.x;
    if (e >= E_EDGES) return;
    int r = row[e], c = col[e];
    float wv = dis[r] * attr[e] * dis[c];
    int p = atomicAdd(&cursor[r], 1);
    ecol[p] = c;
    ew[p]   = wv;
}

// ---------------- Z = [X @ C1 | 1]  (N x 4) ----------------
__global__ void xz_kernel(const float* __restrict__ X, const float* __restrict__ C1,
                          float4* __restrict__ Z) {
    __shared__ float sC[F_FEAT * 3];
    for (int i = threadIdx.x; i < F_FEAT * 3; i += blockDim.x) sC[i] = C1[i];
    __syncthreads();
    int wave = threadIdx.x >> 6;
    int lane = threadIdx.x & 63;
    int rowi = blockIdx.x * (blockDim.x >> 6) + wave;
    if (rowi >= N_NODES) return;
    const float* xr = X + (size_t)rowi * F_FEAT;
    float s0 = 0.f, s1 = 0.f, s2 = 0.f;
    for (int k = lane; k < F_FEAT; k += 64) {
        float xv = xr[k];
        s0 += xv * sC[k * 3 + 0];
        s1 += xv * sC[k * 3 + 1];
        s2 += xv * sC[k * 3 + 2];
    }
    #pragma unroll
    for (int off = 32; off; off >>= 1) {
        s0 += __shfl_down(s0, off);
        s1 += __shfl_down(s1, off);
        s2 += __shfl_down(s2, off);
    }
    if (lane == 0) Z[rowi] = make_float4(s0, s1, s2, 1.0f);
}

// ---------------- CSR SpMM + jacobi combine fused ----------------
// Xout[r] = cf[0]*(A Xin)[r] - cf[1]*Xm1[r] - cf[2]*Xm2[r]
__global__ void spmm_combine_kernel(const int* __restrict__ rowstart, const int* __restrict__ ecol,
                                    const float* __restrict__ ew, const float4* __restrict__ Xin,
                                    const float4* __restrict__ Xm1, const float4* __restrict__ Xm2,
                                    float4* __restrict__ Xout, const float* __restrict__ cf) {
    int rid = blockIdx.x * (blockDim.x >> 4) + (threadIdx.x >> 4);
    int sub = threadIdx.x & 15;
    if (rid >= N_NODES) return;
    int s    = rowstart[rid];
    int epos = rowstart[rid + 1];
    float ax = 0.f, ay = 0.f, az = 0.f, aw = 0.f;
    for (int e = s + sub; e < epos; e += 16) {
        float wv = ew[e];
        float4 v = Xin[ecol[e]];
        ax += wv * v.x; ay += wv * v.y; az += wv * v.z; aw += wv * v.w;
    }
    #pragma unroll
    for (int off = 8; off; off >>= 1) {
        ax += __shfl_xor(ax, off, 16);
        ay += __shfl_xor(ay, off, 16);
        az += __shfl_xor(az, off, 16);
        aw += __shfl_xor(aw, off, 16);
    }
    if (sub == 0) {
        float cA = cf[0], cB = cf[1], cC = cf[2];
        float4 x1 = Xm1[rid], x2 = Xm2[rid];
        Xout[rid] = make_float4(cA * ax - cB * x1.x - cC * x2.x,
                                cA * ay - cB * x1.y - cC * x2.y,
                                cA * az - cB * x1.z - cC * x2.z,
                                cA * aw - cB * x1.w - cC * x2.w);
    }
}

// ---------------- reduce + final fused via ticket ----------------
// Tasks: (node i, rank r), 8 per node. R[r*4+c] = sum_i U0[i,r]*S[i,c],
// S = B0+B1+B2+B3. Last block computes the tiny TRL + log_softmax.
__global__ void reduce_final_kernel(const float* __restrict__ U0, const float4* __restrict__ B0,
                                    const float4* __restrict__ B1, const float4* __restrict__ B2,
                                    const float4* __restrict__ B3, float* __restrict__ R,
                                    int* __restrict__ done, const float* __restrict__ bu,
                                    const float* __restrict__ U2, const float* __restrict__ core,
                                    const float* __restrict__ U3, const float* __restrict__ trl_bias,
                                    float* __restrict__ out) {
    __shared__ float lds[8 * 32];
    int t    = threadIdx.x;                 // block = 512
    int gtid = blockIdx.x * 512 + t;
    int i    = gtid >> 3;
    int r    = gtid & 7;
    float v0 = 0.f, v1 = 0.f, v2 = 0.f, v3 = 0.f;
    if (i < N_NODES) {
        float4 s0 = B0[i], s1 = B1[i], s2 = B2[i], s3 = B3[i];
        float u = U0[(size_t)i * 8 + r];
        v0 = u * (s0.x + s1.x + s2.x + s3.x);
        v1 = u * (s0.y + s1.y + s2.y + s3.y);
        v2 = u * (s0.z + s1.z + s2.z + s3.z);
        v3 = u * (s0.w + s1.w + s2.w + s3.w);
    }
    // reduce over the 8 lanes sharing r (lane bits 3..5)
    #pragma unroll
    for (int off = 8; off <= 32; off <<= 1) {
        v0 += __shfl_xor(v0, off);
        v1 += __shfl_xor(v1, off);
        v2 += __shfl_xor(v2, off);
        v3 += __shfl_xor(v3, off);
    }
    int w = t >> 6, lane = t & 63;
    if (lane < 8) {
        lds[w * 32 + lane * 4 + 0] = v0;
        lds[w * 32 + lane * 4 + 1] = v1;
        lds[w * 32 + lane * 4 + 2] = v2;
        lds[w * 32 + lane * 4 + 3] = v3;
    }
    __syncthreads();
    if (t < 32) {
        float tot = 0.f;
        #pragma unroll
        for (int w2 = 0; w2 < 8; ++w2) tot += lds[w2 * 32 + t];
        atomicAdd(&R[t], tot);
    }
    __syncthreads();
    if (t != 0) return;
    __threadfence();
    int old = atomicAdd(done, 1);
    if (old != (int)gridDim.x - 1) return;
    __threadfence();                        // invalidate L1, see all R atomics

    // ---- final tiny TRL + log_softmax (single thread) ----
    float M[3][8][3];
    for (int rr = 0; rr < 8; ++rr) {
        float q = R[rr * 4 + 3];
        for (int s = 0; s < 3; ++s) {
            M[0][rr][s] = R[rr * 4 + s] + q * bu[0 * 3 + s];
            M[1][rr][s] = q * bu[1 * 3 + s];
            M[2][rr][s] = q * bu[2 * 3 + s];
        }
    }
    float uvec[8];
    for (int u = 0; u < 8; ++u) uvec[u] = 0.f;
    for (int rr = 0; rr < 8; ++rr)
        for (int s = 0; s < 3; ++s)
            for (int tt = 0; tt < 3; ++tt) {
                float rst = 0.f;
                for (int c = 0; c < 3; ++c) rst += M[c][rr][s] * U2[c * 3 + tt];
                const float* cp = core + ((rr * 3 + s) * 3 + tt) * 8;
                for (int u = 0; u < 8; ++u) uvec[u] += rst * cp[u];
            }
    float o[8];
    float mx = -1e30f;
    for (int k = 0; k < 8; ++k) {
        float acc = trl_bias[0];
        for (int u = 0; u < 8; ++u) acc += uvec[u] * U3[k * 8 + u];
        o[k] = acc;
        mx = fmaxf(mx, acc);
    }
    float se = 0.f;
    for (int k = 0; k < 8; ++k) se += expf(o[k] - mx);
    float lse = mx + logf(se);
    for (int k = 0; k < 8; ++k) out[k] = o[k] - lse;
}

extern "C" void kernel_launch(void* const* d_in, const int* in_sizes, int n_in,
                              void* d_out, int out_size, void* d_ws, size_t ws_size,
                              hipStream_t stream) {
    const float* X          = (const float*)d_in[0];
    const int*   edge_index = (const int*)d_in[1];
    const float* edge_attr  = (const float*)d_in[2];
    const float* W1         = (const float*)d_in[3];
    const float* b1         = (const float*)d_in[4];
    const float* b2         = (const float*)d_in[6];
    const float* b3         = (const float*)d_in[8];
    const float* alphas_raw = (const float*)d_in[9];
    const float* core       = (const float*)d_in[10];
    const float* U0         = (const float*)d_in[11];
    const float* U1         = (const float*)d_in[12];
    const float* U2         = (const float*)d_in[13];
    const float* U3         = (const float*)d_in[14];
    const float* trl_bias   = (const float*)d_in[15];

    const int* row = edge_index;            // first E
    const int* col = edge_index + E_EDGES;  // next E

    float* ws   = (float*)d_ws;
    float* cf   = ws + OFF_CF;
    float* bu   = ws + OFF_BU;
    float* R    = ws + OFF_R;
    int*   done = (int*)(ws + OFF_DONE);
    float* C1   = ws + OFF_C1;
    float* dis  = ws + OFF_DIS;   // float degree, then dis in place
    int*   cnt  = (int*)(ws + OFF_CNT);
    int*   rs   = (int*)(ws + OFF_RS);
    int*   cur  = (int*)(ws + OFF_CUR);
    int*   ecol = (int*)(ws + OFF_ECOL);
    float* ew   = ws + OFF_EW;
    float* B0   = ws + OFF_B0;
    float* B1   = ws + OFF_B1;
    float* B2   = ws + OFF_B2;
    float* B3   = ws + OFF_B3;

    const int TB = 256;
    const int gE = (E_EDGES + TB - 1) / TB;
    const int gR = (N_NODES + 15) / 16;     // 16 lanes/row
    const int gRed = (N_NODES * 8 + 511) / 512;   // 120 blocks

    // fused setup: zero deg/cnt + R + done, jacobi coefs, bu, C1
    setup_kernel<<<SETUP_BLOCKS, TB, 0, stream>>>(alphas_raw, b1, b2, b3, U1, W1, ws);

    // CSR build
    hist_kernel<<<gE, TB, 0, stream>>>(row, edge_attr, dis, cnt);
    scan_kernel<<<1, 256, 0, stream>>>(cnt, dis, rs, cur);
    scatter_kernel<<<gE, TB, 0, stream>>>(row, col, edge_attr, dis, cur, ecol, ew);

    // B0 = [X@C1 | 1]
    xz_kernel<<<(N_NODES + 3) / 4, TB, 0, stream>>>(X, C1, (float4*)B0);

    // poly iterations: SpMM + combine fused, no atomics
    spmm_combine_kernel<<<gR, TB, 0, stream>>>(rs, ecol, ew, (const float4*)B0,
                                               (const float4*)B0, (const float4*)B0,
                                               (float4*)B1, cf + 0);
    spmm_combine_kernel<<<gR, TB, 0, stream>>>(rs, ecol, ew, (const float4*)B1,
                                               (const float4*)B1, (const float4*)B0,
                                               (float4*)B2, cf + 3);
    spmm_combine_kernel<<<gR, TB, 0, stream>>>(rs, ecol, ew, (const float4*)B2,
                                               (const float4*)B2, (const float4*)B1,
                                               (float4*)B3, cf + 6);

    // R = U0^T [P | s]; last block does TRL + log_softmax
    reduce_final_kernel<<<gRed, 512, 0, stream>>>(U0, (const float4*)B0, (const float4*)B1,
                                                  (const float4*)B2, (const float4*)B3, R,
                                                  done, bu, U2, core, U3, trl_bias,
                                                  (float*)d_out);
}